// Round 2
// baseline (1037.176 us; speedup 1.0000x reference)
//
#include <hip/hip_runtime.h>
#include <cstdint>

// N=M=2048 windows, L=64, C=256, A=48 asy rows, H=8 heads, dh=32, B=8 CB groups.
#define LN_EPS    1e-5f
#define SCALE_ATT 0.17677669529663688f   // 32^-0.5

#define ZBS  264   // LDS stride (u16) for 48x256 z buffer; 132 words % 32 = 4 -> 2-way max
#define BIGS 780   // LDS stride (u16) for big buffer; 390 words % 32 = 6 -> conflict-free-ish

typedef __bf16 bf16x8 __attribute__((ext_vector_type(8)));
typedef float f32x4 __attribute__((ext_vector_type(4)));
typedef unsigned short us8v __attribute__((ext_vector_type(8)));

__device__ __forceinline__ unsigned short f2bf(float f) {
  unsigned int u = __builtin_bit_cast(unsigned int, f);
  u += 0x7FFFu + ((u >> 16) & 1u);           // RNE
  return (unsigned short)(u >> 16);
}
__device__ __forceinline__ float b2f(unsigned short h) {
  unsigned int u = ((unsigned int)h) << 16;
  return __builtin_bit_cast(float, u);
}
__device__ __forceinline__ bf16x8 ld_frag(const unsigned short* p) {
  us8v u = *(const us8v*)p;
  return __builtin_bit_cast(bf16x8, u);
}
__device__ __forceinline__ float wave_sum(float v) {
#pragma unroll
  for (int m = 1; m < 64; m <<= 1) v += __shfl_xor(v, m, 64);
  return v;
}

// Pack f32 weight W[K][N] -> bf16 wp[(kb*N + c)*32 + ko] = W[kb*32+ko][c]
// so an MFMA B-fragment (col=lane&15, k=(lane>>4)*8+i) is one 16B lane load.
__global__ void pack_w_kernel(const float* __restrict__ W, unsigned short* __restrict__ out,
                              int K, int Ncols) {
  int idx = blockIdx.x * 256 + threadIdx.x;
  if (idx >= K * Ncols) return;
  int kb = idx / (Ncols * 32);
  int rem = idx - kb * (Ncols * 32);
  int c = rem >> 5;
  int ko = rem & 31;
  out[idx] = f2bf(W[(kb * 32 + ko) * Ncols + c]);
}

// C(48 x ...) = A_lds(48 x 32*KB, stride lda) @ Wpack ; wave owns CT col-tiles at col0.
template <int CT, int KB>
__device__ __forceinline__ void gemm48(const unsigned short* A, int lda,
                                       const unsigned short* __restrict__ wp, int ncols,
                                       int col0, int lane, f32x4 (&acc)[3][CT]) {
  const int r16 = lane & 15;
  const int kg = lane >> 4;
#pragma unroll
  for (int kb = 0; kb < KB; ++kb) {
    const int ka = kb * 32 + kg * 8;
    bf16x8 a0 = ld_frag(&A[r16 * lda + ka]);
    bf16x8 a1 = ld_frag(&A[(16 + r16) * lda + ka]);
    bf16x8 a2 = ld_frag(&A[(32 + r16) * lda + ka]);
#pragma unroll
    for (int ct = 0; ct < CT; ++ct) {
      const bf16x8 bfr = ld_frag(&wp[(size_t)(kb * ncols + col0 + ct * 16 + r16) * 32 + kg * 8]);
      acc[0][ct] = __builtin_amdgcn_mfma_f32_16x16x32_bf16(a0, bfr, acc[0][ct], 0, 0, 0);
      acc[1][ct] = __builtin_amdgcn_mfma_f32_16x16x32_bf16(a1, bfr, acc[1][ct], 0, 0, 0);
      acc[2][ct] = __builtin_amdgcn_mfma_f32_16x16x32_bf16(a2, bfr, acc[2][ct], 0, 0, 0);
    }
  }
}

__global__ __launch_bounds__(1024, 4) void fused_window_kernel(
    const float* __restrict__ x, float* __restrict__ out, const int* __restrict__ iw,
    const float* __restrict__ n1g, const float* __restrict__ n1b,
    const float* __restrict__ n2g, const float* __restrict__ n2b,
    const unsigned short* __restrict__ qkvp, const float* __restrict__ qkvb,
    const unsigned short* __restrict__ projp, const float* __restrict__ projb,
    const float* __restrict__ ls1, const float* __restrict__ ls2,
    const unsigned short* __restrict__ m1p, const float* __restrict__ m1b,
    const unsigned short* __restrict__ m2p, const float* __restrict__ m2b,
    float* __restrict__ gsum, const int* __restrict__ ecb) {
  __shared__ __align__(16) unsigned short zb[48 * ZBS];    // z bf16 (lives until proj residual)
  __shared__ __align__(16) unsigned short big[48 * BIGS];  // qkv -> P -> o -> xa + mlp hidden

  const int m = blockIdx.x;
  const int n = iw[m];
  const int tid = threadIdx.x;
  const int w = tid >> 6;        // 16 waves
  const int lane = tid & 63;
  const int r16 = lane & 15;
  const int kg = lane >> 4;
  const f32x4 vzero = {0.f, 0.f, 0.f, 0.f};

  const float* xwin = x + (size_t)n * (64 * 256);
  float* owin = out + (size_t)n * (64 * 256);

  // ---- Phase A: LN1 of pad row (48+w) -> out; z = LN2(LN1(x)) rows w*3..w*3+2 -> zb ----
  {
    float4 g1v = *(const float4*)&n1g[lane * 4];
    float4 b1v = *(const float4*)&n1b[lane * 4];
    // pad row straight to output
    {
      int j = 48 + w;
      float4 xv = *(const float4*)&xwin[(size_t)j * 256 + lane * 4];
      float mu = wave_sum(xv.x + xv.y + xv.z + xv.w) * (1.f / 256.f);
      float d0 = xv.x - mu, d1 = xv.y - mu, d2 = xv.z - mu, d3 = xv.w - mu;
      float r = rsqrtf(wave_sum(d0 * d0 + d1 * d1 + d2 * d2 + d3 * d3) * (1.f / 256.f) + LN_EPS);
      float4 o;
      o.x = d0 * r * g1v.x + b1v.x;
      o.y = d1 * r * g1v.y + b1v.y;
      o.z = d2 * r * g1v.z + b1v.z;
      o.w = d3 * r * g1v.w + b1v.w;
      *(float4*)&owin[(size_t)j * 256 + lane * 4] = o;
    }
    float4 g2v = *(const float4*)&n2g[lane * 4];
    float4 b2v = *(const float4*)&n2b[lane * 4];
#pragma unroll
    for (int i = 0; i < 3; ++i) {
      int j = w * 3 + i;
      float4 xv = *(const float4*)&xwin[(size_t)j * 256 + lane * 4];
      float mu1 = wave_sum(xv.x + xv.y + xv.z + xv.w) * (1.f / 256.f);
      float d0 = xv.x - mu1, d1 = xv.y - mu1, d2 = xv.z - mu1, d3 = xv.w - mu1;
      float r1 = rsqrtf(wave_sum(d0 * d0 + d1 * d1 + d2 * d2 + d3 * d3) * (1.f / 256.f) + LN_EPS);
      float y0 = d0 * r1 * g1v.x + b1v.x, y1 = d1 * r1 * g1v.y + b1v.y;
      float y2 = d2 * r1 * g1v.z + b1v.z, y3 = d3 * r1 * g1v.w + b1v.w;
      float mu2 = wave_sum(y0 + y1 + y2 + y3) * (1.f / 256.f);
      float e0 = y0 - mu2, e1 = y1 - mu2, e2 = y2 - mu2, e3 = y3 - mu2;
      float r2 = rsqrtf(wave_sum(e0 * e0 + e1 * e1 + e2 * e2 + e3 * e3) * (1.f / 256.f) + LN_EPS);
      float z0 = e0 * r2 * g2v.x + b2v.x, z1 = e1 * r2 * g2v.y + b2v.y;
      float z2 = e2 * r2 * g2v.z + b2v.z, z3 = e3 * r2 * g2v.w + b2v.w;
      *(ushort4*)&zb[j * ZBS + lane * 4] = make_ushort4(f2bf(z0), f2bf(z1), f2bf(z2), f2bf(z3));
    }
  }
  __syncthreads();

  // ---- Phase B: QKV = z @ qkv_w + b (48x768); wave owns 48 cols ----
  {
    f32x4 acc[3][3];
#pragma unroll
    for (int i = 0; i < 3; ++i)
#pragma unroll
      for (int j = 0; j < 3; ++j) acc[i][j] = vzero;
    gemm48<3, 8>(zb, ZBS, qkvp, 768, w * 48, lane, acc);
#pragma unroll
    for (int ct = 0; ct < 3; ++ct) {
      int col = w * 48 + ct * 16 + r16;
      float bias = qkvb[col];
#pragma unroll
      for (int rt = 0; rt < 3; ++rt)
#pragma unroll
        for (int rr = 0; rr < 4; ++rr) {
          int row = rt * 16 + kg * 4 + rr;
          big[row * BIGS + col] = f2bf(acc[rt][ct][rr] + bias);
        }
    }
  }
  __syncthreads();

  // ---- Phase C: MFMA attention; wave w<8 = head w (own region: cols w*96..+95) ----
  f32x4 oacc[3][2];
#pragma unroll
  for (int i = 0; i < 3; ++i)
#pragma unroll
    for (int j = 0; j < 2; ++j) oacc[i][j] = vzero;
  if (w < 8) {
    unsigned short* hb = &big[w * 96];
    bf16x8 aq[3], bk[3];
#pragma unroll
    for (int t = 0; t < 3; ++t) {
      aq[t] = ld_frag(&hb[(t * 16 + r16) * BIGS + kg * 8]);         // Q[q][d]
      bk[t] = ld_frag(&hb[(t * 16 + r16) * BIGS + 32 + kg * 8]);    // K[k][d]
    }
    f32x4 s[3][3];
#pragma unroll
    for (int rt = 0; rt < 3; ++rt)
#pragma unroll
      for (int ck = 0; ck < 3; ++ck)
        s[rt][ck] = __builtin_amdgcn_mfma_f32_16x16x32_bf16(aq[rt], bk[ck], vzero, 0, 0, 0);
    // in-register softmax over k (k = ck*16 + r16), write P over Q/K region
#pragma unroll
    for (int rt = 0; rt < 3; ++rt)
#pragma unroll
      for (int rr = 0; rr < 4; ++rr) {
        float a0 = s[rt][0][rr] * SCALE_ATT;
        float a1 = s[rt][1][rr] * SCALE_ATT;
        float a2 = s[rt][2][rr] * SCALE_ATT;
        float mx = fmaxf(fmaxf(a0, a1), a2);
#pragma unroll
        for (int msk = 1; msk < 16; msk <<= 1) mx = fmaxf(mx, __shfl_xor(mx, msk, 64));
        float e0 = __expf(a0 - mx), e1 = __expf(a1 - mx), e2 = __expf(a2 - mx);
        float sm = e0 + e1 + e2;
#pragma unroll
        for (int msk = 1; msk < 16; msk <<= 1) sm += __shfl_xor(sm, msk, 64);
        float inv = 1.f / sm;
        int q = rt * 16 + kg * 4 + rr;
        hb[q * BIGS + r16] = f2bf(e0 * inv);
        hb[q * BIGS + 16 + r16] = f2bf(e1 * inv);
        hb[q * BIGS + 32 + r16] = f2bf(e2 * inv);
      }
    // zero-pad P cols 48..63 (k padding for the second PV k-slice)
#pragma unroll
    for (int i = 0; i < 6; ++i) {
      int lin = i * 64 + lane;
      int qr = lin >> 3;
      int c2 = lin & 7;
      *(unsigned int*)&hb[qr * BIGS + 48 + c2 * 2] = 0u;
    }
    // PV: A = P rows (contiguous), B = V gathered by scalar reads (rows clamped <48)
    bf16x8 pa[3][2];
#pragma unroll
    for (int t = 0; t < 3; ++t)
#pragma unroll
      for (int ks = 0; ks < 2; ++ks)
        pa[t][ks] = ld_frag(&hb[(t * 16 + r16) * BIGS + ks * 32 + kg * 8]);
    bf16x8 bv[2][2];
#pragma unroll
    for (int cd = 0; cd < 2; ++cd)
#pragma unroll
      for (int ks = 0; ks < 2; ++ks) {
        us8v tmp;
#pragma unroll
        for (int i = 0; i < 8; ++i) {
          int kk = ks * 32 + kg * 8 + i;
          int kr = kk < 48 ? kk : 47;   // padded k rows: P==0, read any finite V
          tmp[i] = hb[kr * BIGS + 64 + cd * 16 + r16];
        }
        bv[cd][ks] = __builtin_bit_cast(bf16x8, tmp);
      }
#pragma unroll
    for (int t = 0; t < 3; ++t)
#pragma unroll
      for (int cd = 0; cd < 2; ++cd) {
        oacc[t][cd] = __builtin_amdgcn_mfma_f32_16x16x32_bf16(pa[t][0], bv[cd][0], oacc[t][cd], 0, 0, 0);
        oacc[t][cd] = __builtin_amdgcn_mfma_f32_16x16x32_bf16(pa[t][1], bv[cd][1], oacc[t][cd], 0, 0, 0);
      }
  }
  __syncthreads();   // all P/V reads complete before o overwrites cols 0..255
  if (w < 8) {
#pragma unroll
    for (int t = 0; t < 3; ++t)
#pragma unroll
      for (int cd = 0; cd < 2; ++cd)
#pragma unroll
        for (int rr = 0; rr < 4; ++rr) {
          int row = t * 16 + kg * 4 + rr;
          int col = w * 32 + cd * 16 + r16;   // head w owns o cols w*32..+31
          big[row * BIGS + col] = f2bf(oacc[t][cd][rr]);
        }
  }
  __syncthreads();

  // ---- Phase D: proj; xa = z + ls1*(o @ proj_w + b); xa stays in registers ----
  float xar[3][4];
  {
    f32x4 accp[3][1];
#pragma unroll
    for (int i = 0; i < 3; ++i) accp[i][0] = vzero;
    gemm48<1, 8>(big, BIGS, projp, 256, w * 16, lane, accp);
    int col = w * 16 + r16;
    float bias = projb[col];
    float l1 = ls1[col];
#pragma unroll
    for (int rt = 0; rt < 3; ++rt)
#pragma unroll
      for (int rr = 0; rr < 4; ++rr) {
        int row = rt * 16 + kg * 4 + rr;
        xar[rt][rr] = b2f(zb[row * ZBS + col]) + l1 * (accp[rt][0][rr] + bias);
      }
  }
  __syncthreads();   // all o reads done before xa overwrites cols 0..255
  {
    int col = w * 16 + r16;
#pragma unroll
    for (int rt = 0; rt < 3; ++rt)
#pragma unroll
      for (int rr = 0; rr < 4; ++rr) {
        int row = rt * 16 + kg * 4 + rr;
        big[row * BIGS + col] = f2bf(xar[rt][rr]);
      }
  }
  __syncthreads();

  // ---- Phase E: MLP, hidden 1024 in two halves of 512 (cols 256..767 of big) ----
  f32x4 acc2[3][1];
#pragma unroll
  for (int i = 0; i < 3; ++i) acc2[i][0] = vzero;
#pragma unroll 1
  for (int half = 0; half < 2; ++half) {
    f32x4 acch[3][2];
#pragma unroll
    for (int i = 0; i < 3; ++i)
#pragma unroll
      for (int j = 0; j < 2; ++j) acch[i][j] = vzero;
    gemm48<2, 8>(big, BIGS, m1p, 1024, half * 512 + w * 32, lane, acch);
#pragma unroll
    for (int ct = 0; ct < 2; ++ct) {
      int lcol = w * 32 + ct * 16 + r16;
      float bias = m1b[half * 512 + lcol];
#pragma unroll
      for (int rt = 0; rt < 3; ++rt)
#pragma unroll
        for (int rr = 0; rr < 4; ++rr) {
          int row = rt * 16 + kg * 4 + rr;
          float hv = acch[rt][ct][rr] + bias;
          hv = 0.5f * hv * (1.0f + erff(hv * 0.70710678118654752f));
          big[row * BIGS + 256 + lcol] = f2bf(hv);
        }
    }
    __syncthreads();
    gemm48<1, 16>(big + 256, BIGS, m2p + (size_t)half * 131072, 256, w * 16, lane, acc2);
    __syncthreads();
  }

  // ---- Phase F: out = xa + mfac*ls2*mvec (direct global store); CB col sums ----
  {
    const int cb = *ecb;
    const float mfac = cb ? 0.5f : 1.0f;
    const int g = n >> 8;
    int col = w * 16 + r16;
    float bias = m2b[col];
    float l2 = ls2[col];
    float csum = 0.f;
#pragma unroll
    for (int rt = 0; rt < 3; ++rt)
#pragma unroll
      for (int rr = 0; rr < 4; ++rr) {
        int row = rt * 16 + kg * 4 + rr;
        float mv = acc2[rt][0][rr] + bias;
        owin[(size_t)row * 256 + col] = xar[rt][rr] + mfac * l2 * mv;
        csum += mv;
      }
    csum += __shfl_xor(csum, 16, 64);
    csum += __shfl_xor(csum, 32, 64);
    if (cb && kg == 0) atomicAdd(&gsum[g * 256 + col], csum);
  }
}

// out[n, j<48, :] += 0.5 * ls2 * group_mean  (group = n>>8, mean over 16384 rows)
__global__ void cb_add_kernel(float* __restrict__ out, const float* __restrict__ gsum,
                              const float* __restrict__ ls2, const int* __restrict__ ecb) {
  if (*ecb == 0) return;
  const float sc = 0.5f / 16384.0f;
  int idx = blockIdx.x * blockDim.x + threadIdx.x;
  const int total = 2048 * 48 * 64;  // float4 granules
  for (; idx < total; idx += gridDim.x * blockDim.x) {
    int n = idx / (48 * 64);
    int rem = idx - n * (48 * 64);
    int j = rem >> 6;
    int c4 = rem & 63;
    int g = n >> 8;
    float4 gs = *(const float4*)&gsum[g * 256 + c4 * 4];
    float4 l2 = *(const float4*)&ls2[c4 * 4];
    float* p = &out[((size_t)n * 64 + j) * 256 + c4 * 4];
    float4 v = *(float4*)p;
    v.x += sc * l2.x * gs.x;
    v.y += sc * l2.y * gs.y;
    v.z += sc * l2.z * gs.z;
    v.w += sc * l2.w * gs.w;
    *(float4*)p = v;
  }
}

extern "C" void kernel_launch(void* const* d_in, const int* in_sizes, int n_in,
                              void* d_out, int out_size, void* d_ws, size_t ws_size,
                              hipStream_t stream) {
  const float* x = (const float*)d_in[0];
  const int* iw = (const int*)d_in[1];
  const int* ecb = (const int*)d_in[7];
  const float* n1g = (const float*)d_in[8];
  const float* n1b = (const float*)d_in[9];
  const float* n2g = (const float*)d_in[10];
  const float* n2b = (const float*)d_in[11];
  const float* qkvw = (const float*)d_in[12];
  const float* qkvb = (const float*)d_in[13];
  const float* projw = (const float*)d_in[14];
  const float* projb = (const float*)d_in[15];
  const float* ls1 = (const float*)d_in[16];
  const float* ls2 = (const float*)d_in[17];
  const float* m1w = (const float*)d_in[18];
  const float* m1b = (const float*)d_in[19];
  const float* m2w = (const float*)d_in[20];
  const float* m2b = (const float*)d_in[21];
  float* out = (float*)d_out;

  char* ws = (char*)d_ws;
  unsigned short* qkvp = (unsigned short*)(ws);             // 256x768  -> 393216 B
  unsigned short* projp = (unsigned short*)(ws + 393216);   // 256x256  -> 131072 B
  unsigned short* m1p = (unsigned short*)(ws + 524288);     // 256x1024 -> 524288 B
  unsigned short* m2p = (unsigned short*)(ws + 1048576);    // 1024x256 -> 524288 B
  float* gsum = (float*)(ws + 1572864);                     // 8 x 256 f32

  hipMemsetAsync(gsum, 0, 8 * 256 * sizeof(float), stream);

  pack_w_kernel<<<768, 256, 0, stream>>>(qkvw, qkvp, 256, 768);
  pack_w_kernel<<<256, 256, 0, stream>>>(projw, projp, 256, 256);
  pack_w_kernel<<<1024, 256, 0, stream>>>(m1w, m1p, 256, 1024);
  pack_w_kernel<<<1024, 256, 0, stream>>>(m2w, m2p, 1024, 256);

  fused_window_kernel<<<2048, 1024, 0, stream>>>(x, out, iw, n1g, n1b, n2g, n2b,
                                                 qkvp, qkvb, projp, projb, ls1, ls2,
                                                 m1p, m1b, m2p, m2b, gsum, ecb);

  cb_add_kernel<<<4096, 256, 0, stream>>>(out, gsum, ls2, ecb);
}

// Round 3
// 801.795 us; speedup vs baseline: 1.2936x; 1.2936x over previous
//
#include <hip/hip_runtime.h>
#include <cstdint>

// N=M=2048 windows, L=64, C=256, A=48 asy rows, H=8 heads, dh=32, B=8 CB groups.
#define LN_EPS    1e-5f
#define SCALE_ATT 0.17677669529663688f   // 32^-0.5

#define BIGS 780   // LDS stride (u16); 390 words % 32 = 6

typedef __bf16 bf16x8 __attribute__((ext_vector_type(8)));
typedef float f32x4 __attribute__((ext_vector_type(4)));
typedef unsigned short us8v __attribute__((ext_vector_type(8)));

__device__ __forceinline__ unsigned short f2bf(float f) {
  unsigned int u = __builtin_bit_cast(unsigned int, f);
  u += 0x7FFFu + ((u >> 16) & 1u);           // RNE
  return (unsigned short)(u >> 16);
}
__device__ __forceinline__ float b2f(unsigned short h) {
  unsigned int u = ((unsigned int)h) << 16;
  return __builtin_bit_cast(float, u);
}
__device__ __forceinline__ bf16x8 ld_frag(const unsigned short* p) {
  us8v u = *(const us8v*)p;
  return __builtin_bit_cast(bf16x8, u);
}
__device__ __forceinline__ float wave_sum(float v) {
#pragma unroll
  for (int m = 1; m < 64; m <<= 1) v += __shfl_xor(v, m, 64);
  return v;
}

// Pack f32 weight W[K][N] -> bf16 wp[(kb*N + c)*32 + ko] = W[kb*32+ko][c]
__global__ void pack_w_kernel(const float* __restrict__ W, unsigned short* __restrict__ out,
                              int K, int Ncols) {
  int idx = blockIdx.x * 256 + threadIdx.x;
  if (idx >= K * Ncols) return;
  int kb = idx / (Ncols * 32);
  int rem = idx - kb * (Ncols * 32);
  int c = rem >> 5;
  int ko = rem & 31;
  out[idx] = f2bf(W[(kb * 32 + ko) * Ncols + c]);
}

// qkv pack with column permutation: packed col c' in [Qall|Kall|Vall] order.
// src col = h*96 + r*32 + d where r=c'>>8, h=(c'>>5)&7, d=c'&31.
__global__ void pack_qkv_kernel(const float* __restrict__ W, unsigned short* __restrict__ out) {
  int idx = blockIdx.x * 256 + threadIdx.x;   // K*N = 256*768
  if (idx >= 256 * 768) return;
  int kb = idx / (768 * 32);
  int rem = idx - kb * (768 * 32);
  int c = rem >> 5;
  int ko = rem & 31;
  int src = ((c >> 5) & 7) * 96 + (c >> 8) * 32 + (c & 31);
  out[idx] = f2bf(W[(kb * 32 + ko) * 768 + src]);
}

// C(48 x ...) = A_lds(48 x 32*KB, stride lda) @ Wpack ; wave owns CT col-tiles at col0.
template <int CT, int KB>
__device__ __forceinline__ void gemm48(const unsigned short* A, int lda,
                                       const unsigned short* __restrict__ wp, int ncols,
                                       int col0, int lane, f32x4 (&acc)[3][CT]) {
  const int r16 = lane & 15;
  const int kg = lane >> 4;
#pragma unroll
  for (int kb = 0; kb < KB; ++kb) {
    const int ka = kb * 32 + kg * 8;
    bf16x8 a0 = ld_frag(&A[r16 * lda + ka]);
    bf16x8 a1 = ld_frag(&A[(16 + r16) * lda + ka]);
    bf16x8 a2 = ld_frag(&A[(32 + r16) * lda + ka]);
#pragma unroll
    for (int ct = 0; ct < CT; ++ct) {
      const bf16x8 bfr = ld_frag(&wp[(size_t)(kb * ncols + col0 + ct * 16 + r16) * 32 + kg * 8]);
      acc[0][ct] = __builtin_amdgcn_mfma_f32_16x16x32_bf16(a0, bfr, acc[0][ct], 0, 0, 0);
      acc[1][ct] = __builtin_amdgcn_mfma_f32_16x16x32_bf16(a1, bfr, acc[1][ct], 0, 0, 0);
      acc[2][ct] = __builtin_amdgcn_mfma_f32_16x16x32_bf16(a2, bfr, acc[2][ct], 0, 0, 0);
    }
  }
}

__global__ __launch_bounds__(512, 4) void fused_window_kernel(
    const float* __restrict__ x, float* __restrict__ out, const int* __restrict__ iw,
    const float* __restrict__ n1g, const float* __restrict__ n1b,
    const float* __restrict__ n2g, const float* __restrict__ n2b,
    const unsigned short* __restrict__ qkvp, const float* __restrict__ qkvb,
    const unsigned short* __restrict__ projp, const float* __restrict__ projb,
    const float* __restrict__ ls1, const float* __restrict__ ls2,
    const unsigned short* __restrict__ m1p, const float* __restrict__ m1b,
    const unsigned short* __restrict__ m2p, const float* __restrict__ m2b,
    float* __restrict__ gsum, const int* __restrict__ ecb) {
  // Single 74.9KB buffer -> 2 blocks/CU. Col regions: [0..255 z->Q->P0->O->xa],
  // [256..511 K->P1], [512..767 V]; MLP hidden half reuses 256..767.
  __shared__ __align__(16) unsigned short big[48 * BIGS];

  const int m = blockIdx.x;
  const int n = iw[m];
  const int tid = threadIdx.x;
  const int w = tid >> 6;        // 8 waves
  const int lane = tid & 63;
  const int r16 = lane & 15;
  const int kg = lane >> 4;
  const f32x4 vzero = {0.f, 0.f, 0.f, 0.f};

  const float* xwin = x + (size_t)n * (64 * 256);
  float* owin = out + (size_t)n * (64 * 256);

  // ---- Phase A: pad rows 48+w*2(+1) -> out; z rows w*6..+5 -> big c0..255 AND out(f32) ----
  {
    float4 g1v = *(const float4*)&n1g[lane * 4];
    float4 b1v = *(const float4*)&n1b[lane * 4];
#pragma unroll
    for (int i = 0; i < 2; ++i) {
      int j = 48 + w * 2 + i;
      float4 xv = *(const float4*)&xwin[(size_t)j * 256 + lane * 4];
      float mu = wave_sum(xv.x + xv.y + xv.z + xv.w) * (1.f / 256.f);
      float d0 = xv.x - mu, d1 = xv.y - mu, d2 = xv.z - mu, d3 = xv.w - mu;
      float r = rsqrtf(wave_sum(d0 * d0 + d1 * d1 + d2 * d2 + d3 * d3) * (1.f / 256.f) + LN_EPS);
      float4 o;
      o.x = d0 * r * g1v.x + b1v.x;
      o.y = d1 * r * g1v.y + b1v.y;
      o.z = d2 * r * g1v.z + b1v.z;
      o.w = d3 * r * g1v.w + b1v.w;
      *(float4*)&owin[(size_t)j * 256 + lane * 4] = o;
    }
    float4 g2v = *(const float4*)&n2g[lane * 4];
    float4 b2v = *(const float4*)&n2b[lane * 4];
#pragma unroll
    for (int i = 0; i < 6; ++i) {
      int j = w * 6 + i;
      float4 xv = *(const float4*)&xwin[(size_t)j * 256 + lane * 4];
      float mu1 = wave_sum(xv.x + xv.y + xv.z + xv.w) * (1.f / 256.f);
      float d0 = xv.x - mu1, d1 = xv.y - mu1, d2 = xv.z - mu1, d3 = xv.w - mu1;
      float r1 = rsqrtf(wave_sum(d0 * d0 + d1 * d1 + d2 * d2 + d3 * d3) * (1.f / 256.f) + LN_EPS);
      float y0 = d0 * r1 * g1v.x + b1v.x, y1 = d1 * r1 * g1v.y + b1v.y;
      float y2 = d2 * r1 * g1v.z + b1v.z, y3 = d3 * r1 * g1v.w + b1v.w;
      float mu2 = wave_sum(y0 + y1 + y2 + y3) * (1.f / 256.f);
      float e0 = y0 - mu2, e1 = y1 - mu2, e2 = y2 - mu2, e3 = y3 - mu2;
      float r2 = rsqrtf(wave_sum(e0 * e0 + e1 * e1 + e2 * e2 + e3 * e3) * (1.f / 256.f) + LN_EPS);
      float z0 = e0 * r2 * g2v.x + b2v.x, z1 = e1 * r2 * g2v.y + b2v.y;
      float z2 = e2 * r2 * g2v.z + b2v.z, z3 = e3 * r2 * g2v.w + b2v.w;
      float4 zv; zv.x = z0; zv.y = z1; zv.z = z2; zv.w = z3;
      *(float4*)&owin[(size_t)j * 256 + lane * 4] = zv;   // f32 z for residual read-back
      *(ushort4*)&big[j * BIGS + lane * 4] = make_ushort4(f2bf(z0), f2bf(z1), f2bf(z2), f2bf(z3));
    }
  }
  __syncthreads();   // bar1

  // ---- Phase B: KV -> LDS c256..767 ; Q -> registers (reads z at c0..255) ----
  f32x4 qacc[3][2];
  {
    f32x4 kv[3][4];
#pragma unroll
    for (int i = 0; i < 3; ++i)
#pragma unroll
      for (int j = 0; j < 4; ++j) kv[i][j] = vzero;
    gemm48<4, 8>(big, BIGS, qkvp, 768, 256 + w * 64, lane, kv);
#pragma unroll
    for (int i = 0; i < 3; ++i)
#pragma unroll
      for (int j = 0; j < 2; ++j) qacc[i][j] = vzero;
    gemm48<2, 8>(big, BIGS, qkvp, 768, w * 32, lane, qacc);
    // KV epilogue: LDS col == packed col
#pragma unroll
    for (int ct = 0; ct < 4; ++ct) {
      int cp = 256 + w * 64 + ct * 16 + r16;
      int src = ((cp >> 5) & 7) * 96 + (cp >> 8) * 32 + (cp & 31);
      float bias = qkvb[src];
#pragma unroll
      for (int rt = 0; rt < 3; ++rt)
#pragma unroll
        for (int rr = 0; rr < 4; ++rr) {
          int row = rt * 16 + kg * 4 + rr;
          big[row * BIGS + cp] = f2bf(kv[rt][ct][rr] + bias);
        }
    }
    // Q bias now (kept in regs until after bar2)
#pragma unroll
    for (int ct = 0; ct < 2; ++ct) {
      int cp = w * 32 + ct * 16 + r16;
      int src = ((cp >> 5) & 7) * 96 + (cp & 31);
      float bias = qkvb[src];
#pragma unroll
      for (int rt = 0; rt < 3; ++rt)
#pragma unroll
        for (int rr = 0; rr < 4; ++rr) qacc[rt][ct][rr] += bias;
    }
  }
  __syncthreads();   // bar2: all z reads done

  // ---- write Q over z (c0..255) ----
#pragma unroll
  for (int ct = 0; ct < 2; ++ct) {
    int cp = w * 32 + ct * 16 + r16;
#pragma unroll
    for (int rt = 0; rt < 3; ++rt)
#pragma unroll
      for (int rr = 0; rr < 4; ++rr) {
        int row = rt * 16 + kg * 4 + rr;
        big[row * BIGS + cp] = f2bf(qacc[rt][ct][rr]);
      }
  }
  __syncthreads();   // bar3

  // ---- Phase C: attention, head h = w (self-contained 32-col slices) ----
  {
    unsigned short* Qr = &big[w * 32];
    unsigned short* Kr = &big[256 + w * 32];
    unsigned short* Vr = &big[512 + w * 32];
    bf16x8 aq[3], bk[3];
#pragma unroll
    for (int t = 0; t < 3; ++t) {
      aq[t] = ld_frag(&Qr[(t * 16 + r16) * BIGS + kg * 8]);
      bk[t] = ld_frag(&Kr[(t * 16 + r16) * BIGS + kg * 8]);
    }
    f32x4 s[3][3];
#pragma unroll
    for (int rt = 0; rt < 3; ++rt)
#pragma unroll
      for (int ck = 0; ck < 3; ++ck)
        s[rt][ck] = __builtin_amdgcn_mfma_f32_16x16x32_bf16(aq[rt], bk[ck], vzero, 0, 0, 0);
    // softmax over k (k = ck*16 + r16); P: k0..31 -> Qr cols, k32..47 -> Kr cols
#pragma unroll
    for (int rt = 0; rt < 3; ++rt)
#pragma unroll
      for (int rr = 0; rr < 4; ++rr) {
        float a0 = s[rt][0][rr] * SCALE_ATT;
        float a1 = s[rt][1][rr] * SCALE_ATT;
        float a2 = s[rt][2][rr] * SCALE_ATT;
        float mx = fmaxf(fmaxf(a0, a1), a2);
#pragma unroll
        for (int msk = 1; msk < 16; msk <<= 1) mx = fmaxf(mx, __shfl_xor(mx, msk, 64));
        float e0 = __expf(a0 - mx), e1 = __expf(a1 - mx), e2 = __expf(a2 - mx);
        float sm = e0 + e1 + e2;
#pragma unroll
        for (int msk = 1; msk < 16; msk <<= 1) sm += __shfl_xor(sm, msk, 64);
        float inv = 1.f / sm;
        int q = rt * 16 + kg * 4 + rr;
        Qr[q * BIGS + r16] = f2bf(e0 * inv);
        Qr[q * BIGS + 16 + r16] = f2bf(e1 * inv);
        Kr[q * BIGS + r16] = f2bf(e2 * inv);
      }
    // zero-pad P k=48..63 (Kr cols 16..31)
#pragma unroll
    for (int i = 0; i < 6; ++i) {
      int lin = i * 64 + lane;
      int qr = lin >> 3;
      int c2 = lin & 7;
      *(unsigned int*)&Kr[qr * BIGS + 16 + c2 * 2] = 0u;
    }
    // PV
    bf16x8 pa[3][2];
#pragma unroll
    for (int t = 0; t < 3; ++t) {
      pa[t][0] = ld_frag(&Qr[(t * 16 + r16) * BIGS + kg * 8]);
      pa[t][1] = ld_frag(&Kr[(t * 16 + r16) * BIGS + kg * 8]);
    }
    bf16x8 bv[2][2];
#pragma unroll
    for (int cd = 0; cd < 2; ++cd)
#pragma unroll
      for (int ks = 0; ks < 2; ++ks) {
        us8v tmp;
#pragma unroll
        for (int i = 0; i < 8; ++i) {
          int kk = ks * 32 + kg * 8 + i;
          int kr = kk < 48 ? kk : 47;   // padded rows: P==0
          tmp[i] = Vr[kr * BIGS + cd * 16 + r16];
        }
        bv[cd][ks] = __builtin_bit_cast(bf16x8, tmp);
      }
    f32x4 oacc[3][2];
#pragma unroll
    for (int i = 0; i < 3; ++i)
#pragma unroll
      for (int j = 0; j < 2; ++j) oacc[i][j] = vzero;
#pragma unroll
    for (int t = 0; t < 3; ++t)
#pragma unroll
      for (int cd = 0; cd < 2; ++cd) {
        oacc[t][cd] = __builtin_amdgcn_mfma_f32_16x16x32_bf16(pa[t][0], bv[cd][0], oacc[t][cd], 0, 0, 0);
        oacc[t][cd] = __builtin_amdgcn_mfma_f32_16x16x32_bf16(pa[t][1], bv[cd][1], oacc[t][cd], 0, 0, 0);
      }
    // O (head w -> cols w*32..+31) over own P0 region: wave-local, no barrier needed
#pragma unroll
    for (int t = 0; t < 3; ++t)
#pragma unroll
      for (int cd = 0; cd < 2; ++cd)
#pragma unroll
        for (int rr = 0; rr < 4; ++rr) {
          int row = t * 16 + kg * 4 + rr;
          big[row * BIGS + w * 32 + cd * 16 + r16] = f2bf(oacc[t][cd][rr]);
        }
  }
  __syncthreads();   // bar4

  // ---- Phase D: proj; xa = z(global f32) + ls1*(O @ proj_w + b) ----
  {
    f32x4 accp[3][2];
#pragma unroll
    for (int i = 0; i < 3; ++i)
#pragma unroll
      for (int j = 0; j < 2; ++j) accp[i][j] = vzero;
    gemm48<2, 8>(big, BIGS, projp, 256, w * 32, lane, accp);
    float xar[3][2][4];
#pragma unroll
    for (int ct = 0; ct < 2; ++ct) {
      int col = w * 32 + ct * 16 + r16;
      float bias = projb[col];
      float l1 = ls1[col];
#pragma unroll
      for (int rt = 0; rt < 3; ++rt)
#pragma unroll
        for (int rr = 0; rr < 4; ++rr) {
          int row = rt * 16 + kg * 4 + rr;
          xar[rt][ct][rr] = owin[(size_t)row * 256 + col] + l1 * (accp[rt][ct][rr] + bias);
        }
    }
    __syncthreads();   // bar5: all O reads done
#pragma unroll
    for (int ct = 0; ct < 2; ++ct) {
      int col = w * 32 + ct * 16 + r16;
#pragma unroll
      for (int rt = 0; rt < 3; ++rt)
#pragma unroll
        for (int rr = 0; rr < 4; ++rr) {
          int row = rt * 16 + kg * 4 + rr;
          big[row * BIGS + col] = f2bf(xar[rt][ct][rr]);
        }
    }
  }
  __syncthreads();   // bar6

  // ---- Phase E: MLP; hidden half (48x512) in c256..767 ----
  f32x4 acc2[3][2];
#pragma unroll
  for (int i = 0; i < 3; ++i)
#pragma unroll
    for (int j = 0; j < 2; ++j) acc2[i][j] = vzero;
#pragma unroll 1
  for (int half = 0; half < 2; ++half) {
    f32x4 acch[3][4];
#pragma unroll
    for (int i = 0; i < 3; ++i)
#pragma unroll
      for (int j = 0; j < 4; ++j) acch[i][j] = vzero;
    gemm48<4, 8>(big, BIGS, m1p, 1024, half * 512 + w * 64, lane, acch);
#pragma unroll
    for (int ct = 0; ct < 4; ++ct) {
      int l = w * 64 + ct * 16 + r16;
      float bias = m1b[half * 512 + l];
#pragma unroll
      for (int rt = 0; rt < 3; ++rt)
#pragma unroll
        for (int rr = 0; rr < 4; ++rr) {
          int row = rt * 16 + kg * 4 + rr;
          float hv = acch[rt][ct][rr] + bias;
          hv = 0.5f * hv * (1.0f + erff(hv * 0.70710678118654752f));
          big[row * BIGS + 256 + l] = f2bf(hv);
        }
    }
    __syncthreads();
    gemm48<2, 16>(big + 256, BIGS, m2p + (size_t)half * 131072, 256, w * 32, lane, acc2);
    __syncthreads();
  }

  // ---- Phase F: out = xa(LDS) + mfac*ls2*mvec ; CB col sums ----
  {
    const int cb = *ecb;
    const float mfac = cb ? 0.5f : 1.0f;
    const int g = n >> 8;
#pragma unroll
    for (int ct = 0; ct < 2; ++ct) {
      int col = w * 32 + ct * 16 + r16;
      float bias = m2b[col];
      float l2 = ls2[col];
      float csum = 0.f;
#pragma unroll
      for (int rt = 0; rt < 3; ++rt)
#pragma unroll
        for (int rr = 0; rr < 4; ++rr) {
          int row = rt * 16 + kg * 4 + rr;
          float mv = acc2[rt][ct][rr] + bias;
          owin[(size_t)row * 256 + col] = b2f(big[row * BIGS + col]) + mfac * l2 * mv;
          csum += mv;
        }
      csum += __shfl_xor(csum, 16, 64);
      csum += __shfl_xor(csum, 32, 64);
      if (cb && kg == 0) atomicAdd(&gsum[g * 256 + col], csum);
    }
  }
}

// out[n, j<48, :] += 0.5 * ls2 * group_mean  (group = n>>8, mean over 16384 rows)
__global__ void cb_add_kernel(float* __restrict__ out, const float* __restrict__ gsum,
                              const float* __restrict__ ls2, const int* __restrict__ ecb) {
  if (*ecb == 0) return;
  const float sc = 0.5f / 16384.0f;
  int idx = blockIdx.x * blockDim.x + threadIdx.x;
  const int total = 2048 * 48 * 64;  // float4 granules
  for (; idx < total; idx += gridDim.x * blockDim.x) {
    int n = idx / (48 * 64);
    int rem = idx - n * (48 * 64);
    int j = rem >> 6;
    int c4 = rem & 63;
    int g = n >> 8;
    float4 gs = *(const float4*)&gsum[g * 256 + c4 * 4];
    float4 l2 = *(const float4*)&ls2[c4 * 4];
    float* p = &out[((size_t)n * 64 + j) * 256 + c4 * 4];
    float4 v = *(float4*)p;
    v.x += sc * l2.x * gs.x;
    v.y += sc * l2.y * gs.y;
    v.z += sc * l2.z * gs.z;
    v.w += sc * l2.w * gs.w;
    *(float4*)p = v;
  }
}

extern "C" void kernel_launch(void* const* d_in, const int* in_sizes, int n_in,
                              void* d_out, int out_size, void* d_ws, size_t ws_size,
                              hipStream_t stream) {
  const float* x = (const float*)d_in[0];
  const int* iw = (const int*)d_in[1];
  const int* ecb = (const int*)d_in[7];
  const float* n1g = (const float*)d_in[8];
  const float* n1b = (const float*)d_in[9];
  const float* n2g = (const float*)d_in[10];
  const float* n2b = (const float*)d_in[11];
  const float* qkvw = (const float*)d_in[12];
  const float* qkvb = (const float*)d_in[13];
  const float* projw = (const float*)d_in[14];
  const float* projb = (const float*)d_in[15];
  const float* ls1 = (const float*)d_in[16];
  const float* ls2 = (const float*)d_in[17];
  const float* m1w = (const float*)d_in[18];
  const float* m1b = (const float*)d_in[19];
  const float* m2w = (const float*)d_in[20];
  const float* m2b = (const float*)d_in[21];
  float* out = (float*)d_out;

  char* ws = (char*)d_ws;
  unsigned short* qkvp = (unsigned short*)(ws);             // 256x768  (permuted cols)
  unsigned short* projp = (unsigned short*)(ws + 393216);   // 256x256
  unsigned short* m1p = (unsigned short*)(ws + 524288);     // 256x1024
  unsigned short* m2p = (unsigned short*)(ws + 1048576);    // 1024x256
  float* gsum = (float*)(ws + 1572864);                     // 8 x 256 f32

  hipMemsetAsync(gsum, 0, 8 * 256 * sizeof(float), stream);

  pack_qkv_kernel<<<768, 256, 0, stream>>>(qkvw, qkvp);
  pack_w_kernel<<<256, 256, 0, stream>>>(projw, projp, 256, 256);
  pack_w_kernel<<<1024, 256, 0, stream>>>(m1w, m1p, 256, 1024);
  pack_w_kernel<<<1024, 256, 0, stream>>>(m2w, m2p, 1024, 256);

  fused_window_kernel<<<2048, 512, 0, stream>>>(x, out, iw, n1g, n1b, n2g, n2b,
                                                qkvp, qkvb, projp, projb, ls1, ls2,
                                                m1p, m1b, m2p, m2b, gsum, ecb);

  cb_add_kernel<<<4096, 256, 0, stream>>>(out, gsum, ls2, ecb);
}